// Round 8
// baseline (7207.861 us; speedup 1.0000x reference)
//
#include <hip/hip_runtime.h>
#include <math.h>

#define TSZ (1u << 19)
#define TMASK (TSZ - 1u)

typedef __attribute__((ext_vector_type(8))) short bf8_t;   // 8 bf16 = 4 VGPRs (MFMA A/B frag)
typedef __attribute__((ext_vector_type(4))) float f32x4;   // MFMA C/D frag
typedef _Float16 h2_t __attribute__((ext_vector_type(2))); // packed f16 pair

struct ResArr { float r[8]; };
struct WPtrs { const float* w[7]; };

// f32 -> bf16 bits, RNE
__device__ __forceinline__ unsigned short f2b(float x) {
    unsigned u = __float_as_uint(x);
    return (unsigned short)((u + 0x7fffu + ((u >> 16) & 1u)) >> 16);
}
__device__ __forceinline__ unsigned pack2(float a, float b) {
    return (unsigned)f2b(a) | ((unsigned)f2b(b) << 16);
}

// swizzled LDS address: 64 rows x 128 B; 16B chunk index XORed with row&7.
__device__ __forceinline__ int swadr(int row, int e) {
    return row * 128 + ((((e >> 3) ^ (row & 7)) << 4)) + ((e & 7) << 1);
}

// branchless f32 -> fp8 e4m3 of (x * 2^20), RNE (proven r7-r9)
__device__ __forceinline__ unsigned enc8(float x) {
    float v = x * 1048576.0f;                       // 2^20
    unsigned u = __float_as_uint(v);
    unsigned s = (u >> 24) & 0x80u;
    unsigned ua = u & 0x7fffffffu;
    unsigned r = ua + 0x7ffffu + ((ua >> 20) & 1u); // RNE at bit 20
    int E = (int)(r >> 23) - 120;                   // e_a + 7
    unsigned nrm = ((unsigned)E << 3) | ((r >> 20) & 7u);
    float t = __uint_as_float(ua) * 512.0f + 12582912.0f;  // 1.5*2^23 magic
    unsigned den = __float_as_uint(t) & 0xfu;
    unsigned mag = (__uint_as_float(ua) >= 0.015625f) ? nrm : den;
    return s | mag;
}

// fp8 byte pair-expand + packed f16 FMA of trilinear weight (proven r8/r9)
__device__ __forceinline__ void trilerp8(unsigned u, float wt, h2_t& acc01, h2_t& acc23) {
    unsigned ws = (unsigned)__builtin_bit_cast(unsigned short, (_Float16)wt);
    h2_t w2 = __builtin_bit_cast(h2_t, __builtin_amdgcn_perm(0u, ws, 0x01000100u));
    unsigned p01 = __builtin_amdgcn_perm(0u, u, 0x01040004u);
    unsigned p23 = __builtin_amdgcn_perm(0u, u, 0x03040204u);
    unsigned m01 = (((p01 >> 1) & 0x3F803F80u) + 0x20002000u) | (p01 & 0x80008000u);
    unsigned m23 = (((p23 >> 1) & 0x3F803F80u) + 0x20002000u) | (p23 & 0x80008000u);
    acc01 = __builtin_bit_cast(h2_t, m01) * w2 + acc01;
    acc23 = __builtin_bit_cast(h2_t, m23) * w2 + acc23;
}

// ---------------- merged pre-kernel: tables -> fp8, weights -> frags, zero counters ----------------
__global__ void prep_all(const float4* __restrict__ tbl, uint4* __restrict__ tab_out,
                         WPtrs wp, unsigned short* __restrict__ wfrag,
                         unsigned* __restrict__ cnt) {
    int b = blockIdx.x;
    if (b < 4096) {
        int i = b * 256 + threadIdx.x;   // i < 1048576, 4 table entries each
        uint4 o;
        { float4 v = tbl[4 * i + 0]; o.x = enc8(v.x) | (enc8(v.y) << 8) | (enc8(v.z) << 16) | (enc8(v.w) << 24); }
        { float4 v = tbl[4 * i + 1]; o.y = enc8(v.x) | (enc8(v.y) << 8) | (enc8(v.z) << 16) | (enc8(v.w) << 24); }
        { float4 v = tbl[4 * i + 2]; o.z = enc8(v.x) | (enc8(v.y) << 8) | (enc8(v.z) << 16) | (enc8(v.w) << 24); }
        { float4 v = tbl[4 * i + 3]; o.w = enc8(v.x) | (enc8(v.y) << 8) | (enc8(v.z) << 16) | (enc8(v.w) << 24); }
        tab_out[i] = o;
        return;
    }
    if (b >= 4096 + 72) {                // last block: zero head + done counters
        for (int j = threadIdx.x; j < 1025; j += 256) cnt[j] = 0u;
        return;
    }
    int idx = (b - 4096) * 256 + threadIdx.x;
    if (idx >= 18432) return;
    int layer, base;
    if      (idx < 2048)  { layer = 0; base = 0;     }
    else if (idx < 6144)  { layer = 1; base = 2048;  }
    else if (idx < 7168)  { layer = 2; base = 6144;  }
    else if (idx < 9216)  { layer = 3; base = 7168;  }
    else if (idx < 13312) { layer = 4; base = 9216;  }
    else if (idx < 17408) { layer = 5; base = 13312; }
    else                  { layer = 6; base = 17408; }
    int rel  = idx - base;
    int frag = rel >> 9;
    int r    = rel & 511;
    int lane = r >> 3, j = r & 7;
    int quad = lane >> 4, col16 = lane & 15;
    int KS = (layer == 0 || layer == 3) ? 1 : 2;
    int nt = frag / KS, ks = frag % KS;
    int k = ks * 32 + quad * 8 + j;
    int n = nt * 16 + col16;
    int Kreal = (layer == 0) ? 32 : (layer == 3) ? 31 : 64;
    int Nw    = (layer == 2) ? 16 : (layer == 6) ? 3  : 64;
    float v = 0.0f;
    if (k < Kreal && n < Nw) v = wp.w[layer][k * Nw + n];
    wfrag[idx] = f2b(v);
}

// ---------------- MLP for one 256-point chunk (device fn shared by fused + cleanup) ----------------
// enc reads are agent-scope atomic loads: they bypass the consumer XCD's L2, which may
// hold stale lines (producer ran on a different XCD within the same dispatch). Pattern
// validated on HW in r7 (agent loads correct, ~rate-neutral). No barriers inside: each
// wave owns its LDS tile, so the wave-uniform npts guard is safe.
__device__ __forceinline__ void mlp_block(
    int cblk, int tid, unsigned char* actAll,
    const float* __restrict__ views, const uint2* __restrict__ enc,
    const unsigned short* __restrict__ wfrag,
    const float* __restrict__ b1, const float* __restrict__ b2,
    const float* __restrict__ b3, const float* __restrict__ b4,
    const float* __restrict__ b5, const float* __restrict__ b6,
    const float* __restrict__ b7,
    float* __restrict__ out_col, float* __restrict__ out_den, int npts)
{
    const int w     = tid >> 6;
    const int lane  = tid & 63;
    const int quad  = lane >> 4;
    const int col16 = lane & 15;
    unsigned char* actb = actAll + w * 8192;

    const int n0 = cblk * 256 + w * 64;
    if (n0 >= npts) return;              // wave-uniform, no barriers follow
    int pt = n0 + lane;
    int ptc = pt < npts ? pt : npts - 1;

    float vx = views[3 * ptc + 0], vy = views[3 * ptc + 1], vz = views[3 * ptc + 2];

    // enc -> LDS tile (row=point, cols 0..31 = 8 levels x 4 feats, bf16, swizzled)
#pragma unroll
    for (int lp = 0; lp < 4; ++lp) {
        unsigned long long v0 = __hip_atomic_load(
            (const unsigned long long*)&enc[(size_t)(2 * lp + 0) * npts + ptc],
            __ATOMIC_RELAXED, __HIP_MEMORY_SCOPE_AGENT);
        unsigned long long v1 = __hip_atomic_load(
            (const unsigned long long*)&enc[(size_t)(2 * lp + 1) * npts + ptc],
            __ATOMIC_RELAXED, __HIP_MEMORY_SCOPE_AGENT);
        uint4 pk;
        pk.x = (unsigned)v0; pk.y = (unsigned)(v0 >> 32);
        pk.z = (unsigned)v1; pk.w = (unsigned)(v1 >> 32);
        *(uint4*)(actb + lane * 128 + ((lp ^ (lane & 7)) << 4)) = pk;
    }

#define LAYER_STD(KS, FB, BIAS)                                                          \
    {                                                                                    \
        bf8_t A[4][KS];                                                                  \
        _Pragma("unroll") for (int mt = 0; mt < 4; ++mt)                                 \
            _Pragma("unroll") for (int ks = 0; ks < KS; ++ks)                            \
                A[mt][ks] = *(const bf8_t*)(actb + swadr(mt * 16 + col16, ks * 32 + quad * 8)); \
        _Pragma("unroll") for (int nt = 0; nt < 4; ++nt) {                               \
            float bv = BIAS[nt * 16 + col16];                                            \
            f32x4 acc[4];                                                                \
            _Pragma("unroll") for (int mt = 0; mt < 4; ++mt) acc[mt] = f32x4{bv, bv, bv, bv}; \
            _Pragma("unroll") for (int ks = 0; ks < KS; ++ks) {                          \
                bf8_t B = ((const bf8_t*)(wfrag + FB + (nt * KS + ks) * 512))[lane];     \
                _Pragma("unroll") for (int mt = 0; mt < 4; ++mt)                         \
                    acc[mt] = __builtin_amdgcn_mfma_f32_16x16x32_bf16(A[mt][ks], B, acc[mt], 0, 0, 0); \
            }                                                                            \
            _Pragma("unroll") for (int mt = 0; mt < 4; ++mt)                             \
                _Pragma("unroll") for (int r = 0; r < 4; ++r) {                          \
                    int row = mt * 16 + quad * 4 + r;                                    \
                    *(unsigned short*)(actb + swadr(row, nt * 16 + col16)) =             \
                        f2b(fmaxf(acc[mt][r], 0.0f));                                    \
                }                                                                        \
        }                                                                                \
    }

    LAYER_STD(1, 0, b1)        // L1: 32 -> 64, relu
    LAYER_STD(2, 2048, b2)     // L2: 64 -> 64, relu

    // L3: 64 -> 16, no relu; col0 -> density, cols 1..15 -> act[.][0..14]
    {
        bf8_t A[4][2];
#pragma unroll
        for (int mt = 0; mt < 4; ++mt)
#pragma unroll
            for (int ks = 0; ks < 2; ++ks)
                A[mt][ks] = *(const bf8_t*)(actb + swadr(mt * 16 + col16, ks * 32 + quad * 8));
        float bv = b3[col16];
        f32x4 acc[4];
#pragma unroll
        for (int mt = 0; mt < 4; ++mt) acc[mt] = f32x4{bv, bv, bv, bv};
#pragma unroll
        for (int ks = 0; ks < 2; ++ks) {
            bf8_t B = ((const bf8_t*)(wfrag + 6144 + ks * 512))[lane];
#pragma unroll
            for (int mt = 0; mt < 4; ++mt)
                acc[mt] = __builtin_amdgcn_mfma_f32_16x16x32_bf16(A[mt][ks], B, acc[mt], 0, 0, 0);
        }
#pragma unroll
        for (int mt = 0; mt < 4; ++mt)
#pragma unroll
            for (int r = 0; r < 4; ++r) {
                int row = mt * 16 + quad * 4 + r;
                float v = acc[mt][r];
                if (col16 == 0) {
                    if (n0 + row < npts) out_den[n0 + row] = fmaxf(v, 0.0f);
                } else {
                    *(unsigned short*)(actb + swadr(row, col16 - 1)) = f2b(v);
                }
            }
    }

    // SH4 (after L3 so its 16 regs don't span the layer chain)
    {
        float inv = rsqrtf(vx * vx + vy * vy + vz * vz);
        vx *= inv; vy *= inv; vz *= inv;
        float xx = vx * vx, yy = vy * vy, zz = vz * vz;
        float sh[16];
        sh[0]  = 0.28209479177387814f;
        sh[1]  = -0.48860251190291987f * vy;
        sh[2]  = 0.48860251190291987f * vz;
        sh[3]  = -0.48860251190291987f * vx;
        sh[4]  = 1.0925484305920792f * vx * vy;
        sh[5]  = -1.0925484305920792f * vy * vz;
        sh[6]  = 0.94617469575755997f * zz - 0.31539156525252005f;
        sh[7]  = -1.0925484305920792f * vx * vz;
        sh[8]  = 0.54627421529603959f * (xx - yy);
        sh[9]  = -0.59004358992664352f * vy * (3.0f * xx - yy);
        sh[10] = 2.8906114426405538f * vx * vy * vz;
        sh[11] = -0.45704579946446572f * vy * (4.0f * zz - xx - yy);
        sh[12] = 0.37317633259011546f * vz * (2.0f * zz - 3.0f * xx - 3.0f * yy);
        sh[13] = -0.45704579946446572f * vx * (4.0f * zz - xx - yy);
        sh[14] = 1.4453057213202769f * vz * (xx - yy);
        sh[15] = -0.59004358992664352f * vx * (xx - 3.0f * yy);

#pragma unroll
        for (int i = 0; i < 16; ++i)
            *(unsigned short*)(actb + swadr(lane, 15 + i)) = f2b(sh[i]);
        *(unsigned short*)(actb + swadr(lane, 31)) = 0;
    }

    LAYER_STD(1, 7168, b4)     // L4: 31(+pad) -> 64, relu
    LAYER_STD(2, 9216, b5)     // L5: 64 -> 64, relu
    LAYER_STD(2, 13312, b6)    // L6: 64 -> 64, relu

    // L7: 64 -> 3, sigmoid, store colors
    {
        bf8_t A[4][2];
#pragma unroll
        for (int mt = 0; mt < 4; ++mt)
#pragma unroll
            for (int ks = 0; ks < 2; ++ks)
                A[mt][ks] = *(const bf8_t*)(actb + swadr(mt * 16 + col16, ks * 32 + quad * 8));
        float bv = (col16 < 3) ? b7[col16] : 0.0f;
        f32x4 acc[4];
#pragma unroll
        for (int mt = 0; mt < 4; ++mt) acc[mt] = f32x4{bv, bv, bv, bv};
#pragma unroll
        for (int ks = 0; ks < 2; ++ks) {
            bf8_t B = ((const bf8_t*)(wfrag + 17408 + ks * 512))[lane];
#pragma unroll
            for (int mt = 0; mt < 4; ++mt)
                acc[mt] = __builtin_amdgcn_mfma_f32_16x16x32_bf16(A[mt][ks], B, acc[mt], 0, 0, 0);
        }
        if (col16 < 3) {
#pragma unroll
            for (int mt = 0; mt < 4; ++mt)
#pragma unroll
                for (int r = 0; r < 4; ++r) {
                    int row = mt * 16 + quad * 4 + r;
                    if (n0 + row < npts) {
                        float s = 1.0f / (1.0f + expf(-acc[mt][r]));
                        out_col[(size_t)(n0 + row) * 3 + col16] = s;
                    }
                }
        }
    }
#undef LAYER_STD
}

// ---------------- fused kernel: XCD-partitioned gather + opportunistic MLP claims ----------------
// Gather (unchanged r6 form, plain loads): level = bid&7 pins each level's 2 MB table to
// one XCD's L2 (proven r4: FETCH 310->30 MB); the gather is pinned at the L2 request-rate
// roofline (~109 us) which consumes L2 pipes, NOT CU slots (MfmaUtil 0, VALU 21%).
// So after gathering, each block publishes its chunk (threadfence + done counter) and
// try-claims ready 256-pt MLP chunks (head CAS; ready = done[m>>1]==8). No block ever
// waits: nothing ready -> exit; cleanup kernel handles leftovers. Worst case = serial
// (today's time); expected = MLP hidden under the gather roofline.
// (256,2) mandatory for the MLP path (r2/r3 spill ladder); gather still rate-fed at 2
// blocks/CU: 64 blocks/XCD x ~3k issued requests >> the ~2.4k needed in flight.
__global__ void __launch_bounds__(256, 2) ngp_fused(
    const float* __restrict__ pts, const float* __restrict__ views,
    const unsigned* __restrict__ tab8,
    uint2* __restrict__ enc,
    const unsigned short* __restrict__ wfrag,
    const float* __restrict__ b1, const float* __restrict__ b2,
    const float* __restrict__ b3, const float* __restrict__ b4,
    const float* __restrict__ b5, const float* __restrict__ b6,
    const float* __restrict__ b7,
    ResArr res, float* __restrict__ out_col, float* __restrict__ out_den,
    unsigned* __restrict__ cnt, int npts, int nMlp)
{
    __shared__ unsigned char act[4][8192];   // MLP tile (32 KB); unused during gather
    __shared__ int s_got;
    const int tid = threadIdx.x;
    const int bid = blockIdx.x;
    const int l   = bid & 7;
    const int g   = bid >> 3;
    const int base = g * 512;

    if (base < npts) {
        const int i0 = base + tid;
        const int i1 = i0 + 256;
        const int j0 = i0 < npts ? i0 : npts - 1;
        const int j1 = i1 < npts ? i1 : npts - 1;

        const float rr = res.r[l];
        const unsigned* tl = tab8 + (size_t)l * TSZ;

        uint2    gp[2][4];
        unsigned gs[2][4] = {};
        unsigned meta[2];
        float    tf[2][3];

#pragma unroll
        for (int p = 0; p < 2; ++p) {
            int idx = p ? j1 : j0;
            float px = pts[3 * idx + 0];
            float py = pts[3 * idx + 1];
            float pz = pts[3 * idx + 2];
            float fx = px * rr, fy = py * rr, fz = pz * rr;
            float f0x = floorf(fx), f0y = floorf(fy), f0z = floorf(fz);
            unsigned ix = (unsigned)f0x, iy = (unsigned)f0y, iz = (unsigned)f0z;
            tf[p][0] = fx - f0x; tf[p][1] = fy - f0y; tf[p][2] = fz - f0z;
            unsigned hy  = iy * 2654435761u,  hz  = iz * 805459861u;
            unsigned hy1 = hy + 2654435761u,  hz1 = hz + 805459861u;
            unsigned syz[4] = { hy ^ hz, hy ^ hz1, hy1 ^ hz, hy1 ^ hz1 };
            unsigned mm = (ix & 1u) << 4;
#pragma unroll
            for (int c = 0; c < 4; ++c) {
                unsigned h0 = (ix ^ syz[c]) & TMASK;
                gp[p][c] = ((const uint2*)tl)[h0 >> 1];
                mm |= (h0 & 1u) << c;
            }
            meta[p] = mm;
            if (ix & 1u) {
                unsigned x1 = ix + 1u;
#pragma unroll
                for (int c = 0; c < 4; ++c) gs[p][c] = tl[(x1 ^ syz[c]) & TMASK];
            }
        }

        __builtin_amdgcn_sched_barrier(0);   // all loads issued before any consume

#pragma unroll
        for (int p = 0; p < 2; ++p) {
            float tx = tf[p][0], ty = tf[p][1], tz = tf[p][2];
            float wx1 = tx, wx0 = 1.0f - tx;
            float wy1 = ty, wy0 = 1.0f - ty;
            float wz1 = tz, wz0 = 1.0f - tz;
            float wyz[4] = { wy0 * wz0, wy0 * wz1, wy1 * wz0, wy1 * wz1 };
            unsigned mm = meta[p];
            h2_t acc01 = { (_Float16)0, (_Float16)0 };
            h2_t acc23 = { (_Float16)0, (_Float16)0 };
#pragma unroll
            for (int c = 0; c < 4; ++c) {
                uint2 pr = gp[p][c];
                bool hodd = (mm >> c) & 1u;
                unsigned mine = hodd ? pr.y : pr.x;
                unsigned oth  = hodd ? pr.x : pr.y;
                unsigned nxt  = (mm & 16u) ? gs[p][c] : oth;
                trilerp8(mine, wx0 * wyz[c], acc01, acc23);
                trilerp8(nxt,  wx1 * wyz[c], acc01, acc23);
            }
            const float SC = 9.5367431640625e-07f;  // 2^-20
            float a0 = (float)acc01[0] * SC, a1 = (float)acc01[1] * SC;
            float a2 = (float)acc23[0] * SC, a3 = (float)acc23[1] * SC;
            uint2 o; o.x = pack2(a0, a1); o.y = pack2(a2, a3);
            if (p == 0) { if (i0 < npts) enc[(size_t)l * npts + i0] = o; }
            else        { if (i1 < npts) enc[(size_t)l * npts + i1] = o; }
        }

        // publish: every wave fences its own stores to L3 (wbl2), barrier joins them,
        // then one device-scope increment marks this (chunk, level) done.
        __threadfence();
        __syncthreads();
        if (tid == 0)
            __hip_atomic_fetch_add(&cnt[1 + g], 1u, __ATOMIC_RELEASE, __HIP_MEMORY_SCOPE_AGENT);
    }

    // ---- opportunistic MLP claims (never blocks; leftovers go to cleanup kernel) ----
    while (true) {
        __syncthreads();
        if (tid == 0) {
            int got = -1;
            unsigned h = __hip_atomic_load(&cnt[0], __ATOMIC_RELAXED, __HIP_MEMORY_SCOPE_AGENT);
            while ((int)h < nMlp) {
                if (__hip_atomic_load(&cnt[1 + (h >> 1)], __ATOMIC_RELAXED,
                                      __HIP_MEMORY_SCOPE_AGENT) != 8u) break;
                if (__hip_atomic_compare_exchange_strong(&cnt[0], &h, h + 1,
                        __ATOMIC_RELAXED, __ATOMIC_RELAXED, __HIP_MEMORY_SCOPE_AGENT)) {
                    got = (int)h; break;
                }
            }
            s_got = got;
        }
        __syncthreads();
        if (s_got < 0) break;
        mlp_block(s_got, tid, &act[0][0], views, enc, wfrag,
                  b1, b2, b3, b4, b5, b6, b7, out_col, out_den, npts);
    }
}

// ---------------- cleanup: MLP for chunks the fused kernel didn't claim ----------------
// Launched after ngp_fused on the same stream: head is final, enc fully published
// (kernel-boundary visibility). Claimed chunks exit immediately.
__global__ void __launch_bounds__(256, 2) ngp_mlp_fix(
    const float* __restrict__ views, const uint2* __restrict__ enc,
    const unsigned short* __restrict__ wfrag,
    const float* __restrict__ b1, const float* __restrict__ b2,
    const float* __restrict__ b3, const float* __restrict__ b4,
    const float* __restrict__ b5, const float* __restrict__ b6,
    const float* __restrict__ b7,
    float* __restrict__ out_col, float* __restrict__ out_den,
    const unsigned* __restrict__ cnt, int npts)
{
    __shared__ unsigned char act[4][8192];
    unsigned h = __hip_atomic_load((unsigned*)&cnt[0], __ATOMIC_RELAXED, __HIP_MEMORY_SCOPE_AGENT);
    if ((unsigned)blockIdx.x < h) return;   // already done inside ngp_fused
    mlp_block(blockIdx.x, threadIdx.x, &act[0][0], views, enc, wfrag,
              b1, b2, b3, b4, b5, b6, b7, out_col, out_den, npts);
}

extern "C" void kernel_launch(void* const* d_in, const int* in_sizes, int n_in,
                              void* d_out, int out_size, void* d_ws, size_t ws_size,
                              hipStream_t stream) {
    const float* pts    = (const float*)d_in[0];
    const float* views  = (const float*)d_in[1];
    const float* tables = (const float*)d_in[2];
    const float* W1 = (const float*)d_in[3];  const float* b1 = (const float*)d_in[4];
    const float* W2 = (const float*)d_in[5];  const float* b2 = (const float*)d_in[6];
    const float* W3 = (const float*)d_in[7];  const float* b3 = (const float*)d_in[8];
    const float* W4 = (const float*)d_in[9];  const float* b4 = (const float*)d_in[10];
    const float* W5 = (const float*)d_in[11]; const float* b5 = (const float*)d_in[12];
    const float* W6 = (const float*)d_in[13]; const float* b6 = (const float*)d_in[14];
    const float* W7 = (const float*)d_in[15]; const float* b7 = (const float*)d_in[16];

    const int N = in_sizes[0] / 3;
    float* out = (float*)d_out;
    float* out_col = out;                  // [N,3]
    float* out_den = out + (size_t)3 * N;  // [N]

    // d_ws layout: [0,16MiB) fp8 tables ; [16MiB,+36864) weight frags ;
    //              [16MiB+64KiB, +4.1KiB) counters {head, done[1024]} ;
    //              [17MiB, +8B*8*N) enc features (bf16x4 per level-point)
    unsigned* tab8        = (unsigned*)d_ws;
    unsigned short* wfrag = (unsigned short*)((char*)d_ws + (size_t)(TSZ) * 8 * 4);
    unsigned* cnt         = (unsigned*)((char*)d_ws + (size_t)16 * 1024 * 1024 + 65536);
    uint2* enc            = (uint2*)((char*)d_ws + (size_t)17 * 1024 * 1024);

    WPtrs wp;
    wp.w[0] = W1; wp.w[1] = W2; wp.w[2] = W3; wp.w[3] = W4;
    wp.w[4] = W5; wp.w[5] = W6; wp.w[6] = W7;
    prep_all<<<4096 + 72 + 1, 256, 0, stream>>>((const float4*)tables, (uint4*)tab8, wp, wfrag, cnt);

    ResArr res;
    for (int l = 0; l < 8; ++l)
        res.r[l] = (float)(16.0 * pow(64.0, (double)l / 7.0));

    const int gchunks = (N + 511) / 512;   // 512-pt gather chunks (2 pts/thread)
    const int nMlp    = (N + 255) / 256;   // 256-pt MLP chunks
    ngp_fused<<<gchunks * 8, 256, 0, stream>>>(pts, views, tab8, enc, wfrag,
                                               b1, b2, b3, b4, b5, b6, b7,
                                               res, out_col, out_den, cnt, N, nMlp);
    ngp_mlp_fix<<<nMlp, 256, 0, stream>>>(views, enc, wfrag,
                                          b1, b2, b3, b4, b5, b6, b7,
                                          out_col, out_den, cnt, N);
}

// Round 9
// 292.452 us; speedup vs baseline: 24.6463x; 24.6463x over previous
//
#include <hip/hip_runtime.h>
#include <math.h>

#define TSZ (1u << 19)
#define TMASK (TSZ - 1u)

typedef __attribute__((ext_vector_type(8))) short bf8_t;   // 8 bf16 = 4 VGPRs (MFMA A/B frag)
typedef __attribute__((ext_vector_type(4))) float f32x4;   // MFMA C/D frag
typedef _Float16 h2_t __attribute__((ext_vector_type(2))); // packed f16 pair

struct ResArr { float r[8]; };
struct WPtrs { const float* w[7]; };

// f32 -> bf16 bits, RNE
__device__ __forceinline__ unsigned short f2b(float x) {
    unsigned u = __float_as_uint(x);
    return (unsigned short)((u + 0x7fffu + ((u >> 16) & 1u)) >> 16);
}
__device__ __forceinline__ unsigned pack2(float a, float b) {
    return (unsigned)f2b(a) | ((unsigned)f2b(b) << 16);
}

// swizzled LDS address: 64 rows x 128 B; 16B chunk index XORed with row&7.
__device__ __forceinline__ int swadr(int row, int e) {
    return row * 128 + ((((e >> 3) ^ (row & 7)) << 4)) + ((e & 7) << 1);
}

// branchless f32 -> fp8 e4m3 of (x * 2^20), RNE (proven r7-r9)
__device__ __forceinline__ unsigned enc8(float x) {
    float v = x * 1048576.0f;                       // 2^20
    unsigned u = __float_as_uint(v);
    unsigned s = (u >> 24) & 0x80u;
    unsigned ua = u & 0x7fffffffu;
    unsigned r = ua + 0x7ffffu + ((ua >> 20) & 1u); // RNE at bit 20
    int E = (int)(r >> 23) - 120;                   // e_a + 7
    unsigned nrm = ((unsigned)E << 3) | ((r >> 20) & 7u);
    float t = __uint_as_float(ua) * 512.0f + 12582912.0f;  // 1.5*2^23 magic
    unsigned den = __float_as_uint(t) & 0xfu;
    unsigned mag = (__uint_as_float(ua) >= 0.015625f) ? nrm : den;
    return s | mag;
}

// fp8 byte pair-expand + packed f16 FMA of trilinear weight (proven r8/r9)
__device__ __forceinline__ void trilerp8(unsigned u, float wt, h2_t& acc01, h2_t& acc23) {
    unsigned ws = (unsigned)__builtin_bit_cast(unsigned short, (_Float16)wt);
    h2_t w2 = __builtin_bit_cast(h2_t, __builtin_amdgcn_perm(0u, ws, 0x01000100u));
    unsigned p01 = __builtin_amdgcn_perm(0u, u, 0x01040004u);
    unsigned p23 = __builtin_amdgcn_perm(0u, u, 0x03040204u);
    unsigned m01 = (((p01 >> 1) & 0x3F803F80u) + 0x20002000u) | (p01 & 0x80008000u);
    unsigned m23 = (((p23 >> 1) & 0x3F803F80u) + 0x20002000u) | (p23 & 0x80008000u);
    acc01 = __builtin_bit_cast(h2_t, m01) * w2 + acc01;
    acc23 = __builtin_bit_cast(h2_t, m23) * w2 + acc23;
}

// ---------------- merged pre-kernel: tables -> fp8 (blocks 0..4095), weights -> frags ----------------
__global__ void prep_all(const float4* __restrict__ tbl, uint4* __restrict__ tab_out,
                         WPtrs wp, unsigned short* __restrict__ wfrag) {
    int b = blockIdx.x;
    if (b < 4096) {
        int i = b * 256 + threadIdx.x;   // i < 1048576, 4 table entries each
        uint4 o;
        { float4 v = tbl[4 * i + 0]; o.x = enc8(v.x) | (enc8(v.y) << 8) | (enc8(v.z) << 16) | (enc8(v.w) << 24); }
        { float4 v = tbl[4 * i + 1]; o.y = enc8(v.x) | (enc8(v.y) << 8) | (enc8(v.z) << 16) | (enc8(v.w) << 24); }
        { float4 v = tbl[4 * i + 2]; o.z = enc8(v.x) | (enc8(v.y) << 8) | (enc8(v.z) << 16) | (enc8(v.w) << 24); }
        { float4 v = tbl[4 * i + 3]; o.w = enc8(v.x) | (enc8(v.y) << 8) | (enc8(v.z) << 16) | (enc8(v.w) << 24); }
        tab_out[i] = o;
        return;
    }
    int idx = (b - 4096) * 256 + threadIdx.x;
    if (idx >= 18432) return;
    int layer, base;
    if      (idx < 2048)  { layer = 0; base = 0;     }
    else if (idx < 6144)  { layer = 1; base = 2048;  }
    else if (idx < 7168)  { layer = 2; base = 6144;  }
    else if (idx < 9216)  { layer = 3; base = 7168;  }
    else if (idx < 13312) { layer = 4; base = 9216;  }
    else if (idx < 17408) { layer = 5; base = 13312; }
    else                  { layer = 6; base = 17408; }
    int rel  = idx - base;
    int frag = rel >> 9;
    int r    = rel & 511;
    int lane = r >> 3, j = r & 7;
    int quad = lane >> 4, col16 = lane & 15;
    int KS = (layer == 0 || layer == 3) ? 1 : 2;
    int nt = frag / KS, ks = frag % KS;
    int k = ks * 32 + quad * 8 + j;
    int n = nt * 16 + col16;
    int Kreal = (layer == 0) ? 32 : (layer == 3) ? 31 : 64;
    int Nw    = (layer == 2) ? 16 : (layer == 6) ? 3  : 64;
    float v = 0.0f;
    if (k < Kreal && n < Nw) v = wp.w[layer][k * Nw + n];
    wfrag[idx] = f2b(v);
}

// ---------------- gather kernel: ONE level per block ----------------
// level = blockIdx & 7 -> all blocks touching level l's 2 MB fp8 table land on
// XCD l, whose 4 MB L2 holds it (r4: FETCH 310 MB -> 30 MB).
// PINNED at the L2 request-rate roofline: 25.2 M random line-requests / ~96
// req/cyc chip = 109 us, measured invariant across occupancy configs (r4 = r6
// null at 2 pt/thread) and cache-path annotations (r7: agent-scope loads still
// consume the same XCD L2 request slot, +3%). r8: producer-consumer overlap via
// in-kernel global handshake is fatally expensive (per-block __threadfence ->
// 7 ms). Do not retry these.
__global__ void __launch_bounds__(256, 6) hash_gather(
    const float* __restrict__ pts, const unsigned* __restrict__ tab8,
    uint2* __restrict__ enc, ResArr res, int npts)
{
    const int bid = blockIdx.x;
    const int l   = bid & 7;
    const int i   = (bid >> 3) * 256 + threadIdx.x;
    if (i >= npts) return;

    const float px = pts[3 * i + 0];
    const float py = pts[3 * i + 1];
    const float pz = pts[3 * i + 2];

    const float rr = res.r[l];
    float fx = px * rr, fy = py * rr, fz = pz * rr;
    float f0x = floorf(fx), f0y = floorf(fy), f0z = floorf(fz);
    unsigned ix = (unsigned)f0x, iy = (unsigned)f0y, iz = (unsigned)f0z;
    float tx = fx - f0x, ty = fy - f0y, tz = fz - f0z;

    unsigned hy  = iy * 2654435761u,  hz  = iz * 805459861u;
    unsigned hy1 = hy + 2654435761u,  hz1 = hz + 805459861u;
    unsigned syz[4] = { hy ^ hz, hy ^ hz1, hy1 ^ hz, hy1 ^ hz1 };
    const unsigned* tl = tab8 + (size_t)l * TSZ;

    // issue all loads in one burst (pair trick: PRIMES[0]==1 -> x0 even shares
    // an aligned 8B pair with x0+1; odd x0 lanes add exec-masked singles)
    uint2    gp[4];
    unsigned gs[4] = {};
    unsigned mm = (ix & 1u) << 4;
#pragma unroll
    for (int c = 0; c < 4; ++c) {
        unsigned h0 = (ix ^ syz[c]) & TMASK;
        gp[c] = ((const uint2*)tl)[h0 >> 1];
        mm |= (h0 & 1u) << c;
    }
    if (ix & 1u) {
        unsigned x1 = ix + 1u;
#pragma unroll
        for (int c = 0; c < 4; ++c) gs[c] = tl[(x1 ^ syz[c]) & TMASK];
    }

    float wx1 = tx, wx0 = 1.0f - tx;
    float wy1 = ty, wy0 = 1.0f - ty;
    float wz1 = tz, wz0 = 1.0f - tz;
    float wyz[4] = { wy0 * wz0, wy0 * wz1, wy1 * wz0, wy1 * wz1 };

    h2_t acc01 = { (_Float16)0, (_Float16)0 };
    h2_t acc23 = { (_Float16)0, (_Float16)0 };
#pragma unroll
    for (int c = 0; c < 4; ++c) {
        uint2 pr = gp[c];
        bool hodd = (mm >> c) & 1u;
        unsigned mine = hodd ? pr.y : pr.x;     // corner (x0  ,y,z)
        unsigned oth  = hodd ? pr.x : pr.y;     // entry at h0^1 (= x0+1 iff x0 even)
        unsigned nxt  = (mm & 16u) ? gs[c] : oth;
        trilerp8(mine, wx0 * wyz[c], acc01, acc23);
        trilerp8(nxt,  wx1 * wyz[c], acc01, acc23);
    }
    const float SC = 9.5367431640625e-07f;  // 2^-20
    float a0 = (float)acc01[0] * SC, a1 = (float)acc01[1] * SC;
    float a2 = (float)acc23[0] * SC, a3 = (float)acc23[1] * SC;
    uint2 o; o.x = pack2(a0, a1); o.y = pack2(a2, a3);
    enc[(size_t)l * npts + i] = o;
}

// ---------------- MLP kernel (wave-cooperative MFMA) ----------------
// __launch_bounds__ MUST stay (256,2). Evidence ladder: (256,4) -> 240 MB spill
// writes; (256,3) -> 160 MB spill + first-dispatch scratch-touch stall (even
// though arch VGPR showed 84 — the unified arch+accum allocation is what blows
// the 170-reg budget); (256,2) in round 0 with MORE live state -> ~10 MB.
// This kernel is MFMA+LDS with streaming loads; it does not need >8 waves/CU.
__global__ void __launch_bounds__(256, 2) ngp_mlp(
    const float* __restrict__ views,
    const uint2* __restrict__ enc,
    const unsigned short* __restrict__ wfrag,
    const float* __restrict__ b1, const float* __restrict__ b2,
    const float* __restrict__ b3, const float* __restrict__ b4,
    const float* __restrict__ b5, const float* __restrict__ b6,
    const float* __restrict__ b7,
    float* __restrict__ out_col, float* __restrict__ out_den,
    int npts)
{
    __shared__ unsigned char act[4][8192];     // per-wave swizzled tile, 32 KB/block
    const int tid   = threadIdx.x;
    const int w     = tid >> 6;
    const int lane  = tid & 63;
    const int quad  = lane >> 4;
    const int col16 = lane & 15;
    unsigned char* actb = act[w];

    const int n0 = blockIdx.x * 256 + w * 64;
    if (n0 >= npts) return;
    int pt = n0 + lane;
    int ptc = pt < npts ? pt : npts - 1;

    float vx = views[3 * ptc + 0], vy = views[3 * ptc + 1], vz = views[3 * ptc + 2];

    // enc -> LDS tile (row=point, cols 0..31 = 8 levels x 4 feats, bf16, swizzled)
#pragma unroll
    for (int lp = 0; lp < 4; ++lp) {
        uint2 e0 = enc[(size_t)(2 * lp + 0) * npts + ptc];
        uint2 e1 = enc[(size_t)(2 * lp + 1) * npts + ptc];
        uint4 pk;
        pk.x = e0.x; pk.y = e0.y; pk.z = e1.x; pk.w = e1.y;
        *(uint4*)(actb + lane * 128 + ((lp ^ (lane & 7)) << 4)) = pk;
    }

    // ---- MLP layers (all A-frags read before any write) ----
#define LAYER_STD(KS, FB, BIAS)                                                          \
    {                                                                                    \
        bf8_t A[4][KS];                                                                  \
        _Pragma("unroll") for (int mt = 0; mt < 4; ++mt)                                 \
            _Pragma("unroll") for (int ks = 0; ks < KS; ++ks)                            \
                A[mt][ks] = *(const bf8_t*)(actb + swadr(mt * 16 + col16, ks * 32 + quad * 8)); \
        _Pragma("unroll") for (int nt = 0; nt < 4; ++nt) {                               \
            float bv = BIAS[nt * 16 + col16];                                            \
            f32x4 acc[4];                                                                \
            _Pragma("unroll") for (int mt = 0; mt < 4; ++mt) acc[mt] = f32x4{bv, bv, bv, bv}; \
            _Pragma("unroll") for (int ks = 0; ks < KS; ++ks) {                          \
                bf8_t B = ((const bf8_t*)(wfrag + FB + (nt * KS + ks) * 512))[lane];     \
                _Pragma("unroll") for (int mt = 0; mt < 4; ++mt)                         \
                    acc[mt] = __builtin_amdgcn_mfma_f32_16x16x32_bf16(A[mt][ks], B, acc[mt], 0, 0, 0); \
            }                                                                            \
            _Pragma("unroll") for (int mt = 0; mt < 4; ++mt)                             \
                _Pragma("unroll") for (int r = 0; r < 4; ++r) {                          \
                    int row = mt * 16 + quad * 4 + r;                                    \
                    *(unsigned short*)(actb + swadr(row, nt * 16 + col16)) =             \
                        f2b(fmaxf(acc[mt][r], 0.0f));                                    \
                }                                                                        \
        }                                                                                \
    }

    LAYER_STD(1, 0, b1)        // L1: 32 -> 64, relu
    LAYER_STD(2, 2048, b2)     // L2: 64 -> 64, relu

    // L3: 64 -> 16, no relu; col0 -> density, cols 1..15 -> act[.][0..14]
    {
        bf8_t A[4][2];
#pragma unroll
        for (int mt = 0; mt < 4; ++mt)
#pragma unroll
            for (int ks = 0; ks < 2; ++ks)
                A[mt][ks] = *(const bf8_t*)(actb + swadr(mt * 16 + col16, ks * 32 + quad * 8));
        float bv = b3[col16];
        f32x4 acc[4];
#pragma unroll
        for (int mt = 0; mt < 4; ++mt) acc[mt] = f32x4{bv, bv, bv, bv};
#pragma unroll
        for (int ks = 0; ks < 2; ++ks) {
            bf8_t B = ((const bf8_t*)(wfrag + 6144 + ks * 512))[lane];
#pragma unroll
            for (int mt = 0; mt < 4; ++mt)
                acc[mt] = __builtin_amdgcn_mfma_f32_16x16x32_bf16(A[mt][ks], B, acc[mt], 0, 0, 0);
        }
#pragma unroll
        for (int mt = 0; mt < 4; ++mt)
#pragma unroll
            for (int r = 0; r < 4; ++r) {
                int row = mt * 16 + quad * 4 + r;
                float v = acc[mt][r];
                if (col16 == 0) {
                    if (n0 + row < npts) out_den[n0 + row] = fmaxf(v, 0.0f);
                } else {
                    *(unsigned short*)(actb + swadr(row, col16 - 1)) = f2b(v);
                }
            }
    }

    // ---- SH4 (after L3 so its 16 regs don't span the layer chain) ----
    {
        float inv = rsqrtf(vx * vx + vy * vy + vz * vz);
        vx *= inv; vy *= inv; vz *= inv;
        float xx = vx * vx, yy = vy * vy, zz = vz * vz;
        float sh[16];
        sh[0]  = 0.28209479177387814f;
        sh[1]  = -0.48860251190291987f * vy;
        sh[2]  = 0.48860251190291987f * vz;
        sh[3]  = -0.48860251190291987f * vx;
        sh[4]  = 1.0925484305920792f * vx * vy;
        sh[5]  = -1.0925484305920792f * vy * vz;
        sh[6]  = 0.94617469575755997f * zz - 0.31539156525252005f;
        sh[7]  = -1.0925484305920792f * vx * vz;
        sh[8]  = 0.54627421529603959f * (xx - yy);
        sh[9]  = -0.59004358992664352f * vy * (3.0f * xx - yy);
        sh[10] = 2.8906114426405538f * vx * vy * vz;
        sh[11] = -0.45704579946446572f * vy * (4.0f * zz - xx - yy);
        sh[12] = 0.37317633259011546f * vz * (2.0f * zz - 3.0f * xx - 3.0f * yy);
        sh[13] = -0.45704579946446572f * vx * (4.0f * zz - xx - yy);
        sh[14] = 1.4453057213202769f * vz * (xx - yy);
        sh[15] = -0.59004358992664352f * vx * (xx - 3.0f * yy);

        // color input cols 15..30 = sh, col 31 = 0
#pragma unroll
        for (int i = 0; i < 16; ++i)
            *(unsigned short*)(actb + swadr(lane, 15 + i)) = f2b(sh[i]);
        *(unsigned short*)(actb + swadr(lane, 31)) = 0;
    }

    LAYER_STD(1, 7168, b4)     // L4: 31(+pad) -> 64, relu
    LAYER_STD(2, 9216, b5)     // L5: 64 -> 64, relu
    LAYER_STD(2, 13312, b6)    // L6: 64 -> 64, relu

    // L7: 64 -> 3 (cols 3..15 zero pads), sigmoid, store colors
    {
        bf8_t A[4][2];
#pragma unroll
        for (int mt = 0; mt < 4; ++mt)
#pragma unroll
            for (int ks = 0; ks < 2; ++ks)
                A[mt][ks] = *(const bf8_t*)(actb + swadr(mt * 16 + col16, ks * 32 + quad * 8));
        float bv = (col16 < 3) ? b7[col16] : 0.0f;
        f32x4 acc[4];
#pragma unroll
        for (int mt = 0; mt < 4; ++mt) acc[mt] = f32x4{bv, bv, bv, bv};
#pragma unroll
        for (int ks = 0; ks < 2; ++ks) {
            bf8_t B = ((const bf8_t*)(wfrag + 17408 + ks * 512))[lane];
#pragma unroll
            for (int mt = 0; mt < 4; ++mt)
                acc[mt] = __builtin_amdgcn_mfma_f32_16x16x32_bf16(A[mt][ks], B, acc[mt], 0, 0, 0);
        }
        if (col16 < 3) {
#pragma unroll
            for (int mt = 0; mt < 4; ++mt)
#pragma unroll
                for (int r = 0; r < 4; ++r) {
                    int row = mt * 16 + quad * 4 + r;
                    if (n0 + row < npts) {
                        float s = 1.0f / (1.0f + expf(-acc[mt][r]));
                        out_col[(size_t)(n0 + row) * 3 + col16] = s;
                    }
                }
        }
    }
#undef LAYER_STD
}

extern "C" void kernel_launch(void* const* d_in, const int* in_sizes, int n_in,
                              void* d_out, int out_size, void* d_ws, size_t ws_size,
                              hipStream_t stream) {
    const float* pts    = (const float*)d_in[0];
    const float* views  = (const float*)d_in[1];
    const float* tables = (const float*)d_in[2];
    const float* W1 = (const float*)d_in[3];  const float* b1 = (const float*)d_in[4];
    const float* W2 = (const float*)d_in[5];  const float* b2 = (const float*)d_in[6];
    const float* W3 = (const float*)d_in[7];  const float* b3 = (const float*)d_in[8];
    const float* W4 = (const float*)d_in[9];  const float* b4 = (const float*)d_in[10];
    const float* W5 = (const float*)d_in[11]; const float* b5 = (const float*)d_in[12];
    const float* W6 = (const float*)d_in[13]; const float* b6 = (const float*)d_in[14];
    const float* W7 = (const float*)d_in[15]; const float* b7 = (const float*)d_in[16];

    const int N = in_sizes[0] / 3;
    float* out = (float*)d_out;
    float* out_col = out;                  // [N,3]
    float* out_den = out + (size_t)3 * N;  // [N]

    // d_ws layout: [0,16MiB) fp8 tables ; [16MiB,+36864) weight frags ;
    //              [17MiB, +8B*8*N) enc features (bf16x4 per level-point)
    unsigned* tab8        = (unsigned*)d_ws;
    unsigned short* wfrag = (unsigned short*)((char*)d_ws + (size_t)(TSZ) * 8 * 4);
    uint2* enc            = (uint2*)((char*)d_ws + (size_t)17 * 1024 * 1024);

    WPtrs wp;
    wp.w[0] = W1; wp.w[1] = W2; wp.w[2] = W3; wp.w[3] = W4;
    wp.w[4] = W5; wp.w[5] = W6; wp.w[6] = W7;
    prep_all<<<4096 + 72, 256, 0, stream>>>((const float4*)tables, (uint4*)tab8, wp, wfrag);

    ResArr res;
    for (int l = 0; l < 8; ++l)
        res.r[l] = (float)(16.0 * pow(64.0, (double)l / 7.0));

    const int chunks = (N + 255) / 256;
    hash_gather<<<chunks * 8, 256, 0, stream>>>(pts, tab8, enc, res, N);
    ngp_mlp<<<chunks, 256, 0, stream>>>(views, enc, wfrag,
                                        b1, b2, b3, b4, b5, b6, b7,
                                        out_col, out_den, N);
}